// Round 13
// baseline (69.523 us; speedup 1.0000x reference)
//
#include <hip/hip_runtime.h>

constexpr int Bn = 65536;   // rows (entity pairs)
constexpr int Cn = 512;     // relation classes

#define L2E 1.4426950408889634f
#define LN2 0.6931471805599453f

typedef float f32x4 __attribute__((ext_vector_type(4)));

// Global->LDS DMA: no VGPR destination, so the register allocator cannot
// serialize the pipeline. HW writes lane l's 16B to ldsbase + l*16.
__device__ __forceinline__ void gl2lds16(const float* g, float* l) {
  __builtin_amdgcn_global_load_lds(
      (const __attribute__((address_space(1))) void*)g,
      (__attribute__((address_space(3))) void*)l, 16, 0, 0);
}

__device__ __forceinline__ uint32_t lds_addr(const void* p) {
  return (uint32_t)(uintptr_t)(__attribute__((address_space(3))) const char*)(const char*)p;
}

// DPP lane-shuffle on the VALU pipe (zero DS-pipe traffic).
template <int Ctrl, int RowMask>
__device__ __forceinline__ float dpp_get(float x, float ident) {
  return __int_as_float(__builtin_amdgcn_update_dpp(
      __float_as_int(ident), __float_as_int(x), Ctrl, RowMask, 0xf, false));
}

// Endpoint of the slot-size gradient (2->4->8 KB all improved): 16KB slots.
// 128-thread blocks (2 waves); per wave 2 slots x 16KB (4 rows each) = 32KB.
// 512 blocks x 64KB LDS -> exactly 2 blocks/CU, one generation. Steady state
// vmcnt(16): one full 16KB slot in flight across every compute phase.
// Each wave owns 64 contiguous rows, processed in 16 rounds of 4 rows.
__global__ __launch_bounds__(128) void matloss_main(
    const float* __restrict__ logits,
    const float* __restrict__ labels,
    double* __restrict__ acc) {

  const int lane = threadIdx.x & 63;
  const int wib  = threadIdx.x >> 6;            // 0 or 1
  const int gw   = blockIdx.x * 2 + wib;        // 1024 waves, all resident
  constexpr int IT = 16;                        // rounds (4 rows each)
  const size_t row0 = (size_t)gw * 64;          // contiguous 64-row block

  __shared__ float smem[2 * 2 * 4096];          // 64KB: [wave][slot][4096 f32]
  float* slot0 = &smem[wib * 8192];             // slot: 4 rows x {lg lo,lg hi,lb lo,lb hi}
  float* slot1 = slot0 + 4096;

  auto stage = [&](int i, float* slot) {        // 16 vmem ops, 16KB, zero VGPRs
#pragma unroll
    for (int r = 0; r < 4; ++r) {
      const size_t row = row0 + 4 * i + r;
      const float* gl = logits + row * Cn + lane * 4;
      const float* gb = labels + row * Cn + lane * 4;
      float* s = slot + r * 1024;
      gl2lds16(gl,       s);
      gl2lds16(gl + 256, s + 256);
      gl2lds16(gb,       s + 512);
      gl2lds16(gb + 256, s + 768);
    }
  };

  stage(0, slot0);                              // prologue: 32 loads in flight
  stage(1, slot1);

  const uint32_t a0 = lds_addr(slot0) + lane * 16;
  const uint32_t a1 = a0 + 16384;

  float a_term = 0.f, a_cnt = 0.f, a_l2 = 0.f;

#pragma unroll
  for (int i = 0; i < IT; ++i) {
    if (i == IT - 1) asm volatile("s_waitcnt vmcnt(0)" ::: "memory");
    else             asm volatile("s_waitcnt vmcnt(16)" ::: "memory"); // counted, never 0
    __builtin_amdgcn_sched_barrier(0);

    f32x4 q[16];                                // 4 rows x {lg lo, lg hi, lb lo, lb hi}
    const uint32_t va = (i & 1) ? a1 : a0;
    asm volatile(
        "ds_read_b128 %0,  %16\n\t"
        "ds_read_b128 %1,  %16 offset:1024\n\t"
        "ds_read_b128 %2,  %16 offset:2048\n\t"
        "ds_read_b128 %3,  %16 offset:3072\n\t"
        "ds_read_b128 %4,  %16 offset:4096\n\t"
        "ds_read_b128 %5,  %16 offset:5120\n\t"
        "ds_read_b128 %6,  %16 offset:6144\n\t"
        "ds_read_b128 %7,  %16 offset:7168\n\t"
        "ds_read_b128 %8,  %16 offset:8192\n\t"
        "ds_read_b128 %9,  %16 offset:9216\n\t"
        "ds_read_b128 %10, %16 offset:10240\n\t"
        "ds_read_b128 %11, %16 offset:11264\n\t"
        "ds_read_b128 %12, %16 offset:12288\n\t"
        "ds_read_b128 %13, %16 offset:13312\n\t"
        "ds_read_b128 %14, %16 offset:14336\n\t"
        "ds_read_b128 %15, %16 offset:15360"
        : "=&v"(q[0]),  "=&v"(q[1]),  "=&v"(q[2]),  "=&v"(q[3]),
          "=&v"(q[4]),  "=&v"(q[5]),  "=&v"(q[6]),  "=&v"(q[7]),
          "=&v"(q[8]),  "=&v"(q[9]),  "=&v"(q[10]), "=&v"(q[11]),
          "=&v"(q[12]), "=&v"(q[13]), "=&v"(q[14]), "=&v"(q[15])
        : "v"(va));
    asm volatile("s_waitcnt lgkmcnt(0)" ::: "memory");
    __builtin_amdgcn_sched_barrier(0);          // rule #18: no consumer hoisting

    if (i + 2 < IT) stage(i + 2, (i & 1) ? slot1 : slot0);  // refill under compute

    float P[4], S[4], PM[4], CN[4], xz[4];
#pragma unroll
    for (int r = 0; r < 4; ++r) {               // 4 rows' chains interleave
      f32x4 xa = q[4 * r], xb = q[4 * r + 1], la = q[4 * r + 2], lc = q[4 * r + 3];
      float x[8] = {xa.x, xa.y, xa.z, xa.w, xb.x, xb.y, xb.z, xb.w};
      float l[8] = {la.x, la.y, la.z, la.w, lc.x, lc.y, lc.z, lc.w};
      xz[r] = __int_as_float(__builtin_amdgcn_readfirstlane(__float_as_int(x[0])));
      if (lane == 0) l[0] = 0.f;                // threshold class: label forced 0

      // P  = prod over positives of (1 + exp(-|x|));  PM = sum pos min(x,0)
      // S  = sum over negatives of exp(x)  (no-max LSE: |x| < ~6)
      float Pr = 1.f, Sr = 0.f, PMr = 0.f, CNr = 0.f;
#pragma unroll
      for (int k = 0; k < 8; ++k) {
        bool  pos = (l[k] != 0.f);
        float sel = pos ? -fabsf(x[k]) : x[k];
        float e   = __builtin_amdgcn_exp2f(sel * L2E);
        Pr  *= fmaf(l[k], e, 1.f);
        Sr  += pos ? 0.f : e;
        PMr  = fmaf(l[k], fminf(x[k], 0.f), PMr);
        CNr += l[k];
      }
      P[r] = Pr; S[r] = Sr; PM[r] = PMr; CN[r] = CNr;
    }

    // wave64 reduce on VALU pipe: 16 independent chains (4 rows x 4 vars)
#define RED16(CTRL, RM)                                       \
    _Pragma("unroll")                                         \
    for (int r = 0; r < 4; ++r) {                             \
      S[r]  += dpp_get<CTRL, RM>(S[r],  0.f);                 \
      CN[r] += dpp_get<CTRL, RM>(CN[r], 0.f);                 \
      PM[r] += dpp_get<CTRL, RM>(PM[r], 0.f);                 \
      P[r]  *= dpp_get<CTRL, RM>(P[r],  1.f);                 \
    }
    RED16(0x111, 0xf)                           // row_shr:1
    RED16(0x112, 0xf)                           // row_shr:2
    RED16(0x114, 0xf)                           // row_shr:4
    RED16(0x118, 0xf)                           // row_shr:8
    RED16(0x142, 0xa)                           // row_bcast:15 (rows 1,3)
    RED16(0x143, 0xc)                           // row_bcast:31 (rows 2,3)
#undef RED16

#pragma unroll
    for (int r = 0; r < 4; ++r) {
      float Sw  = __int_as_float(__builtin_amdgcn_readlane(__float_as_int(S[r]),  63));
      float CNw = __int_as_float(__builtin_amdgcn_readlane(__float_as_int(CN[r]), 63));
      float PMw = __int_as_float(__builtin_amdgcn_readlane(__float_as_int(PM[r]), 63));
      float Pw  = __int_as_float(__builtin_amdgcn_readlane(__float_as_int(P[r]),  63));

      a_l2 += LN2 * __builtin_amdgcn_logf(Sw) - xz[r];   // lse - x0
      if (CNw > 0.f) {                          // wave-uniform branch
        float t0  = __builtin_amdgcn_exp2f(-fabsf(xz[r]) * L2E);
        float ls0 = fminf(-xz[r], 0.f) - LN2 * __builtin_amdgcn_logf(1.f + t0);
        a_term += ls0 + PMw - LN2 * __builtin_amdgcn_logf(Pw);
        a_cnt  += 1.f + CNw;
      }
    }
  }

  // block reduce: reuse staging LDS (all staging reads done; barrier first)
  __syncthreads();
  if (lane == 0) { smem[wib] = a_term; smem[2 + wib] = a_cnt; smem[4 + wib] = a_l2; }
  __syncthreads();
  if (threadIdx.x == 0) {
    atomicAdd(&acc[0], (double)(smem[0] + smem[1]));
    atomicAdd(&acc[1], (double)(smem[2] + smem[3]));
    atomicAdd(&acc[2], (double)(smem[4] + smem[5]));
  }
}

__global__ void matloss_final(const double* __restrict__ acc, float* __restrict__ out) {
  out[0] = (float)(-acc[0] / acc[1] + acc[2] / (double)Bn);
}

extern "C" void kernel_launch(void* const* d_in, const int* in_sizes, int n_in,
                              void* d_out, int out_size, void* d_ws, size_t ws_size,
                              hipStream_t stream) {
  const float* logits = (const float*)d_in[0];
  const float* labels = (const float*)d_in[1];
  float* out = (float*)d_out;
  double* acc = (double*)d_ws;

  hipMemsetAsync(d_ws, 0, 3 * sizeof(double), stream);  // zero accumulators (capture-safe)
  matloss_main<<<512, 128, 0, stream>>>(logits, labels, acc);
  matloss_final<<<1, 1, 0, stream>>>(acc, out);
}